// Round 6
// baseline (1289.958 us; speedup 1.0000x reference)
//
#include <hip/hip_runtime.h>

#define L_HW (128*128)

__device__ __forceinline__ int transp(int p){ return ((p&7)<<3)|(p>>3); }

// ================= K1: in_proj GEMM quarters (+conv+silu for xc) =================
// LDS floats: XIN[64p][68] @0 ; WBUF[64oc][64] @4352 ; XCP[64d][65] @8448 ; XOUT[64p][68] overlays XIN
#define K1_XIN  0
#define K1_WBUF 4352
#define K1_XCP  8448
#define K1_XOUT 0
#define K1_SMEM 12608

__global__ __launch_bounds__(512, 4)
void k1_gemm(const float* __restrict__ x,
             const float* __restrict__ in_proj_w,
             const float* __restrict__ conv_w,
             const float* __restrict__ conv_b,
             float* __restrict__ xct_g,   // [win][64p][128d]
             float* __restrict__ z_g)     // [win][128d][64p]
{
    __shared__ float sm[K1_SMEM];
    const int t = threadIdx.x;
    const int win = blockIdx.x >> 2, q = blockIdx.x & 3;
    const int b = win >> 8, ih = (win >> 4) & 15, iw = win & 15;
    const float* xwin = x + ((size_t)b*64)*L_HW + ih*8*128 + iw*8;

    // stage XIN[p][ch] stride 68
    {
        const int ch = t >> 3, r = t & 7;
        const float* src = xwin + (size_t)ch*L_HW + r*128;
        float4 v0 = *(const float4*)(src);
        float4 v1 = *(const float4*)(src + 4);
        float* dst = sm + K1_XIN + ch;
        const int p0 = r*8;
        dst[(p0+0)*68]=v0.x; dst[(p0+1)*68]=v0.y; dst[(p0+2)*68]=v0.z; dst[(p0+3)*68]=v0.w;
        dst[(p0+4)*68]=v1.x; dst[(p0+5)*68]=v1.y; dst[(p0+6)*68]=v1.z; dst[(p0+7)*68]=v1.w;
    }
    // stage WBUF rows q*64 .. q*64+63
    {
        const float* wsrc = in_proj_w + q*4096;
        *(float4*)(sm + K1_WBUF + t*4)        = *(const float4*)(wsrc + t*4);
        *(float4*)(sm + K1_WBUF + (t+512)*4)  = *(const float4*)(wsrc + (t+512)*4);
    }
    __syncthreads();

    const int p = t & 63, og = t >> 6;
    float a0=0,a1=0,a2=0,a3=0,a4=0,a5=0,a6=0,a7=0;
    {
        const float* wrow = sm + K1_WBUF + og*8*64;
#define K1ACC(J, A) { float4 wv = *(const float4*)(wrow + (J)*64 + chq*4); \
        A = fmaf(xv.x,wv.x, fmaf(xv.y,wv.y, fmaf(xv.z,wv.z, fmaf(xv.w,wv.w, A)))); }
        #pragma unroll
        for (int chq = 0; chq < 16; ++chq) {
            float4 xv = *(const float4*)(sm + K1_XIN + p*68 + chq*4);
            K1ACC(0,a0) K1ACC(1,a1) K1ACC(2,a2) K1ACC(3,a3)
            K1ACC(4,a4) K1ACC(5,a5) K1ACC(6,a6) K1ACC(7,a7)
        }
#undef K1ACC
    }

    if (q >= 2) {   // z quarters: store and done
        float* zw = z_g + (size_t)win*8192 + ((q-2)*64)*64 + p;
        zw[(og*8+0)*64]=a0; zw[(og*8+1)*64]=a1; zw[(og*8+2)*64]=a2; zw[(og*8+3)*64]=a3;
        zw[(og*8+4)*64]=a4; zw[(og*8+5)*64]=a5; zw[(og*8+6)*64]=a6; zw[(og*8+7)*64]=a7;
        return;
    }

    // xc quarters: park in XCP[dloc][65]
    {
        float* xp = sm + K1_XCP + og*8*65 + p;
        xp[0]=a0; xp[65]=a1; xp[130]=a2; xp[195]=a3;
        xp[260]=a4; xp[325]=a5; xp[390]=a6; xp[455]=a7;
    }
    __syncthreads();

    // depthwise 3x3 conv + silu -> XOUT[p][68]
    {
        const int dloc = t & 63, qq = t >> 6;
        const int dg = q*64 + dloc;
        const float* cwp = conv_w + dg*9;
        const float c0=cwp[0],c1=cwp[1],c2=cwp[2],c3=cwp[3],c4=cwp[4],
                    c5=cwp[5],c6=cwp[6],c7=cwp[7],c8=cwp[8];
        const float cb = conv_b[dg];
        const float* xc = sm + K1_XCP + dloc*65;
        #pragma unroll
        for (int jj = 0; jj < 8; ++jj) {
            const int px = qq*8 + jj;
            const int r = px >> 3, c = px & 7;
            float a = cb;
            if (r > 0) {
                if (c > 0) a = fmaf(xc[px-9], c0, a);
                a = fmaf(xc[px-8], c1, a);
                if (c < 7) a = fmaf(xc[px-7], c2, a);
            }
            if (c > 0) a = fmaf(xc[px-1], c3, a);
            a = fmaf(xc[px], c4, a);
            if (c < 7) a = fmaf(xc[px+1], c5, a);
            if (r < 7) {
                if (c > 0) a = fmaf(xc[px+7], c6, a);
                a = fmaf(xc[px+8], c7, a);
                if (c < 7) a = fmaf(xc[px+9], c8, a);
            }
            sm[K1_XOUT + px*68 + dloc] = a / (1.f + __expf(-a));
        }
    }
    __syncthreads();

    // store xct (coalesced)
    {
        float* dst = xct_g + (size_t)win*8192 + q*64;
        #pragma unroll
        for (int i = 0; i < 2; ++i) {
            const int idx4 = i*512 + t;
            const int pp = idx4 >> 4, dg = idx4 & 15;
            float4 v = *(const float4*)(sm + K1_XOUT + pp*68 + dg*4);
            *(float4*)(dst + pp*128 + dg*4) = v;
        }
    }
}

// ================= K2: x_proj GEMM, one (win,k) per block =================
// LDS: XT[64p][64] swz @0 (4096) ; XDOUT[64l][37] @4096 (2368)
#define K2_XD 4096
#define K2_SMEM 6464

__global__ __launch_bounds__(256, 4)
void k2_xproj(const float* __restrict__ xct_g,
              const float* __restrict__ x_proj_w,
              float* __restrict__ xdbl_g)   // [win][4k][64l][36]
{
    __shared__ float sm[K2_SMEM];
    const int t = threadIdx.x;
    const int win = blockIdx.x >> 2, k = blockIdx.x & 3;
    const int p = t & 63, jg = t >> 6;
    float a0=0,a1=0,a2=0,a3=0,a4=0,a5=0,a6=0,a7=0,a8=0;

    #pragma unroll
    for (int h = 0; h < 2; ++h) {
        __syncthreads();
        #pragma unroll
        for (int i = 0; i < 4; ++i) {
            const int idx4 = i*256 + t;
            const int pp = idx4 >> 4, dg = idx4 & 15;
            float4 v = *(const float4*)(xct_g + (size_t)win*8192 + pp*128 + h*64 + dg*4);
            *(float4*)(sm + pp*64 + ((dg ^ (pp&7))<<2)) = v;
        }
        __syncthreads();
        const float* wb = x_proj_w + (k*36 + jg*9)*128 + h*64;
#define K2ACC(J, A) { float4 wv = *(const float4*)(wb + (J)*128 + dg*4); \
        A = fmaf(xv.x,wv.x, fmaf(xv.y,wv.y, fmaf(xv.z,wv.z, fmaf(xv.w,wv.w, A)))); }
        #pragma unroll
        for (int dg = 0; dg < 16; ++dg) {
            float4 xv = *(const float4*)(sm + p*64 + ((dg ^ (p&7))<<2));
            K2ACC(0,a0) K2ACC(1,a1) K2ACC(2,a2) K2ACC(3,a3) K2ACC(4,a4)
            K2ACC(5,a5) K2ACC(6,a6) K2ACC(7,a7) K2ACC(8,a8)
        }
#undef K2ACC
    }
    __syncthreads();

    // scatter into LDS in scan order (pad-37 rows)
    {
        const int l = (k==0) ? p : (k==1) ? transp(p) : (k==2) ? (63-p) : (63 - transp(p));
        float* dp = sm + K2_XD + l*37 + jg*9;
        dp[0]=a0; dp[1]=a1; dp[2]=a2; dp[3]=a3; dp[4]=a4;
        dp[5]=a5; dp[6]=a6; dp[7]=a7; dp[8]=a8;
    }
    __syncthreads();

    // coalesced linear store: [64l][36]
    {
        float* dst = xdbl_g + ((size_t)win*4 + k)*2304;
        #pragma unroll
        for (int i = 0; i < 9; ++i) {
            const int idx = i*256 + t;
            const int l2 = idx / 36, c = idx - l2*36;
            dst[idx] = sm[K2_XD + l2*37 + c];
        }
    }
}

// ================= K3: scan + merge + LN + gate + out_proj =================
#define K3_XD 0        // [4k][64l][36] = 9216
#define K3_YM 9216     // [128d][65]    = 8320
#define K3_MU 17536
#define K3_RS 17600
#define K3_SMEM 17664

__global__ __launch_bounds__(512, 4)
void k3_scan(const float* __restrict__ xct_g,
             const float* __restrict__ z_g,
             const float* __restrict__ xdbl_g,
             const float* __restrict__ dt_projs_w,
             const float* __restrict__ dt_projs_b,
             const float* __restrict__ A_logs,
             const float* __restrict__ Ds,
             const float* __restrict__ ln_g,
             const float* __restrict__ ln_b,
             const float* __restrict__ out_proj_w,
             float* __restrict__ out)
{
    __shared__ float sm[K3_SMEM];
    const int t = threadIdx.x;
    const int win = blockIdx.x;

    // stage xdbl into LDS; zero YM
    #pragma unroll
    for (int i = 0; i < 5; ++i) {
        const int idx4 = i*512 + t;
        if (idx4 < 2304) {
            float4 v = *(const float4*)(xdbl_g + (size_t)win*9216 + idx4*4);
            *(float4*)(sm + K3_XD + idx4*4) = v;
        }
    }
    for (int i = t; i < 8320; i += 512) sm[K3_YM + i] = 0.f;
    __syncthreads();

    // ---- scan: thread = (k,d), 16 states each ----
    {
        const int k = t >> 7, d = t & 127;
        const int kd = t;
        const float* alp = A_logs + kd*16;
        const float A0 = -__expf(alp[0]);
        bool fast = true;
        #pragma unroll
        for (int s = 1; s < 16; ++s) {
            float a = -__expf(alp[s]);
            fast = fast && (fabsf(a - (float)(s+1)*A0) <= 1e-4f * fabsf(a));
        }
        const float4 wv = *(const float4*)(dt_projs_w + kd*4);
        const float dtb = dt_projs_b[kd];
        const float Dv  = Ds[kd];
        float h0=0,h1=0,h2=0,h3=0,h4=0,h5=0,h6=0,h7=0,
              h8=0,h9=0,h10=0,h11=0,h12=0,h13=0,h14=0,h15=0;
        const float* XDk = sm + K3_XD + k*2304;
        const float* ub = xct_g + (size_t)win*8192 + d;

#define HSTEP(I, E, BC, CC) { h##I = fmaf(h##I, (E), dtu*(BC)); y = fmaf(h##I, (CC), y); }

        if (fast) {
            for (int l = 0; l < 64; ++l) {
                const float* row = XDk + l*36;
                float4 d4 = *(const float4*)(row);
                float4 b0 = *(const float4*)(row+4),  b1 = *(const float4*)(row+8);
                float4 b2 = *(const float4*)(row+12), b3 = *(const float4*)(row+16);
                float4 c0 = *(const float4*)(row+20), c1 = *(const float4*)(row+24);
                float4 c2 = *(const float4*)(row+28), c3 = *(const float4*)(row+32);
                float dtraw = dtb + wv.x*d4.x + wv.y*d4.y + wv.z*d4.z + wv.w*d4.w;
                float dt = (dtraw > 20.f) ? dtraw : __logf(1.f + __expf(dtraw));
                const int lr = 63 - l;
                const int p = (k==0)?l : (k==1)?transp(l) : (k==2)?lr : transp(lr);
                const float u = ub[p*128];
                const float dtu = dt * u;
                const float r  = __expf(dt * A0);
                const float r2 = r*r, r4 = r2*r2, r8 = r4*r4;
                const float e3 = r2*r, e5 = r4*r, e6 = r4*r2, e7 = r4*e3;
                const float e9 = r8*r, e10 = r8*r2, e11 = r8*e3, e12 = r8*r4;
                const float e13 = r8*e5, e14 = r8*e6, e15 = r8*e7, e16 = r8*r8;
                float y = Dv * u;
                HSTEP(0,  r,   b0.x, c0.x)  HSTEP(1,  r2,  b0.y, c0.y)
                HSTEP(2,  e3,  b0.z, c0.z)  HSTEP(3,  r4,  b0.w, c0.w)
                HSTEP(4,  e5,  b1.x, c1.x)  HSTEP(5,  e6,  b1.y, c1.y)
                HSTEP(6,  e7,  b1.z, c1.z)  HSTEP(7,  r8,  b1.w, c1.w)
                HSTEP(8,  e9,  b2.x, c2.x)  HSTEP(9,  e10, b2.y, c2.y)
                HSTEP(10, e11, b2.z, c2.z)  HSTEP(11, e12, b2.w, c2.w)
                HSTEP(12, e13, b3.x, c3.x)  HSTEP(13, e14, b3.y, c3.y)
                HSTEP(14, e15, b3.z, c3.z)  HSTEP(15, e16, b3.w, c3.w)
                atomicAdd(&sm[K3_YM + d*65 + p], y);
            }
        } else {
            const float A1=-__expf(alp[1]), A2=-__expf(alp[2]), A3=-__expf(alp[3]),
                        A4=-__expf(alp[4]), A5=-__expf(alp[5]), A6=-__expf(alp[6]),
                        A7=-__expf(alp[7]), A8=-__expf(alp[8]), A9=-__expf(alp[9]),
                        A10=-__expf(alp[10]), A11=-__expf(alp[11]), A12=-__expf(alp[12]),
                        A13=-__expf(alp[13]), A14=-__expf(alp[14]), A15=-__expf(alp[15]);
            for (int l = 0; l < 64; ++l) {
                const float* row = XDk + l*36;
                float4 d4 = *(const float4*)(row);
                float4 b0 = *(const float4*)(row+4),  b1 = *(const float4*)(row+8);
                float4 b2 = *(const float4*)(row+12), b3 = *(const float4*)(row+16);
                float4 c0 = *(const float4*)(row+20), c1 = *(const float4*)(row+24);
                float4 c2 = *(const float4*)(row+28), c3 = *(const float4*)(row+32);
                float dtraw = dtb + wv.x*d4.x + wv.y*d4.y + wv.z*d4.z + wv.w*d4.w;
                float dt = (dtraw > 20.f) ? dtraw : __logf(1.f + __expf(dtraw));
                const int lr = 63 - l;
                const int p = (k==0)?l : (k==1)?transp(l) : (k==2)?lr : transp(lr);
                const float u = ub[p*128];
                const float dtu = dt * u;
                float y = Dv * u;
                HSTEP(0,  __expf(dt*A0),  b0.x, c0.x)  HSTEP(1,  __expf(dt*A1),  b0.y, c0.y)
                HSTEP(2,  __expf(dt*A2),  b0.z, c0.z)  HSTEP(3,  __expf(dt*A3),  b0.w, c0.w)
                HSTEP(4,  __expf(dt*A4),  b1.x, c1.x)  HSTEP(5,  __expf(dt*A5),  b1.y, c1.y)
                HSTEP(6,  __expf(dt*A6),  b1.z, c1.z)  HSTEP(7,  __expf(dt*A7),  b1.w, c1.w)
                HSTEP(8,  __expf(dt*A8),  b2.x, c2.x)  HSTEP(9,  __expf(dt*A9),  b2.y, c2.y)
                HSTEP(10, __expf(dt*A10), b2.z, c2.z)  HSTEP(11, __expf(dt*A11), b2.w, c2.w)
                HSTEP(12, __expf(dt*A12), b3.x, c3.x)  HSTEP(13, __expf(dt*A13), b3.y, c3.y)
                HSTEP(14, __expf(dt*A14), b3.z, c3.z)  HSTEP(15, __expf(dt*A15), b3.w, c3.w)
                atomicAdd(&sm[K3_YM + d*65 + p], y);
            }
        }
#undef HSTEP
    }
    __syncthreads();

    // ---- LN stats: 8 lanes per pixel ----
    {
        const int px = t >> 3, j = t & 7;
        float s1 = 0.f, s2 = 0.f;
        #pragma unroll
        for (int i = 0; i < 16; ++i) {
            float v = sm[K3_YM + (j*16 + i)*65 + px];
            s1 += v; s2 += v*v;
        }
        s1 += __shfl_xor(s1,1); s2 += __shfl_xor(s2,1);
        s1 += __shfl_xor(s1,2); s2 += __shfl_xor(s2,2);
        s1 += __shfl_xor(s1,4); s2 += __shfl_xor(s2,4);
        if (j == 0) {
            float mu  = s1 * 0.0078125f;
            float var = s2 * 0.0078125f - mu*mu;
            sm[K3_MU + px] = mu;
            sm[K3_RS + px] = rsqrtf(var + 1e-5f);
        }
    }
    __syncthreads();

    // ---- yhat = LN(y) * silu(z), in place ----
    {
        const int p = t & 63, dblk = (t >> 6) * 16;
        const float mu = sm[K3_MU + p], rs = sm[K3_RS + p];
        const float* zb = z_g + (size_t)win*8192 + p;
        #pragma unroll
        for (int i = 0; i < 16; ++i) {
            const int d = dblk + i;
            float yv = sm[K3_YM + d*65 + p];
            float yh = (yv - mu)*rs*ln_g[d] + ln_b[d];
            float zv = zb[d*64];
            sm[K3_YM + d*65 + p] = yh * (zv / (1.f + __expf(-zv)));
        }
    }
    __syncthreads();

    // ---- out_proj: thread = (p, m-octet) ----
    {
        const int p = t & 63, m0 = (t >> 6) * 8;
        float o0=0,o1=0,o2=0,o3=0,o4=0,o5=0,o6=0,o7=0;
#define OACC(J, O) { float4 wq = *(const float4*)(out_proj_w + (m0+(J))*128 + dq*4); \
        O = fmaf(y0,wq.x, fmaf(y1,wq.y, fmaf(y2,wq.z, fmaf(y3,wq.w, O)))); }
        #pragma unroll
        for (int dq = 0; dq < 32; ++dq) {
            float y0 = sm[K3_YM + (dq*4+0)*65 + p];
            float y1 = sm[K3_YM + (dq*4+1)*65 + p];
            float y2 = sm[K3_YM + (dq*4+2)*65 + p];
            float y3 = sm[K3_YM + (dq*4+3)*65 + p];
            OACC(0,o0) OACC(1,o1) OACC(2,o2) OACC(3,o3)
            OACC(4,o4) OACC(5,o5) OACC(6,o6) OACC(7,o7)
        }
#undef OACC
        const int b = win >> 8, ih = (win>>4)&15, iw = win&15;
        float* op = out + ((size_t)b*64)*L_HW + (ih*8 + (p>>3))*128 + iw*8 + (p&7);
        op[(size_t)(m0+0)*L_HW]=o0; op[(size_t)(m0+1)*L_HW]=o1;
        op[(size_t)(m0+2)*L_HW]=o2; op[(size_t)(m0+3)*L_HW]=o3;
        op[(size_t)(m0+4)*L_HW]=o4; op[(size_t)(m0+5)*L_HW]=o5;
        op[(size_t)(m0+6)*L_HW]=o6; op[(size_t)(m0+7)*L_HW]=o7;
    }
}

extern "C" void kernel_launch(void* const* d_in, const int* in_sizes, int n_in,
                              void* d_out, int out_size, void* d_ws, size_t ws_size,
                              hipStream_t stream) {
    const float* x          = (const float*)d_in[0];
    const float* in_proj_w  = (const float*)d_in[1];
    const float* conv_w     = (const float*)d_in[2];
    const float* conv_b     = (const float*)d_in[3];
    const float* x_proj_w   = (const float*)d_in[4];
    const float* dt_projs_w = (const float*)d_in[5];
    const float* dt_projs_b = (const float*)d_in[6];
    const float* A_logs     = (const float*)d_in[7];
    const float* Ds         = (const float*)d_in[8];
    const float* ln_g       = (const float*)d_in[9];
    const float* ln_b       = (const float*)d_in[10];
    const float* out_proj_w = (const float*)d_in[11];
    float* out = (float*)d_out;

    float* xct  = (float*)d_ws;            // 512*8192
    float* zb   = xct + 4194304;           // 512*8192
    float* xdbl = zb  + 4194304;           // 512*4*64*36

    k1_gemm<<<dim3(2048), dim3(512), 0, stream>>>(x, in_proj_w, conv_w, conv_b, xct, zb);
    k2_xproj<<<dim3(2048), dim3(256), 0, stream>>>(xct, x_proj_w, xdbl);
    k3_scan<<<dim3(512), dim3(512), 0, stream>>>(
        xct, zb, xdbl, dt_projs_w, dt_projs_b, A_logs, Ds, ln_g, ln_b,
        out_proj_w, out);
}

// Round 7
// 208.672 us; speedup vs baseline: 6.1817x; 6.1817x over previous
//
#include <hip/hip_runtime.h>

#define L_HW (128*128)

__device__ __forceinline__ int transp(int p){ return ((p&7)<<3)|(p>>3); }

// ================= K1: in_proj GEMM quarters (+conv+silu for xc) =================
// LDS floats: XIN[64p][68] @0 ; WBUF[64oc][64] @4352 ; XCP[64d][65] @8448 ; XOUT[64p][68] overlays XIN
#define K1_XIN  0
#define K1_WBUF 4352
#define K1_XCP  8448
#define K1_XOUT 0
#define K1_SMEM 12608

__global__ __launch_bounds__(512, 4)
void k1_gemm(const float* __restrict__ x,
             const float* __restrict__ in_proj_w,
             const float* __restrict__ conv_w,
             const float* __restrict__ conv_b,
             float* __restrict__ xct_g,   // [win][64p][128d]
             float* __restrict__ z_g)     // [win][128d][64p]
{
    __shared__ float sm[K1_SMEM];
    const int t = threadIdx.x;
    const int win = blockIdx.x >> 2, q = blockIdx.x & 3;
    const int b = win >> 8, ih = (win >> 4) & 15, iw = win & 15;
    const float* xwin = x + ((size_t)b*64)*L_HW + ih*8*128 + iw*8;

    // stage XIN[p][ch] stride 68
    {
        const int ch = t >> 3, r = t & 7;
        const float* src = xwin + (size_t)ch*L_HW + r*128;
        float4 v0 = *(const float4*)(src);
        float4 v1 = *(const float4*)(src + 4);
        float* dst = sm + K1_XIN + ch;
        const int p0 = r*8;
        dst[(p0+0)*68]=v0.x; dst[(p0+1)*68]=v0.y; dst[(p0+2)*68]=v0.z; dst[(p0+3)*68]=v0.w;
        dst[(p0+4)*68]=v1.x; dst[(p0+5)*68]=v1.y; dst[(p0+6)*68]=v1.z; dst[(p0+7)*68]=v1.w;
    }
    // stage WBUF rows q*64 .. q*64+63
    {
        const float* wsrc = in_proj_w + q*4096;
        *(float4*)(sm + K1_WBUF + t*4)        = *(const float4*)(wsrc + t*4);
        *(float4*)(sm + K1_WBUF + (t+512)*4)  = *(const float4*)(wsrc + (t+512)*4);
    }
    __syncthreads();

    const int p = t & 63, og = t >> 6;
    float a0=0,a1=0,a2=0,a3=0,a4=0,a5=0,a6=0,a7=0;
    {
        const float* wrow = sm + K1_WBUF + og*8*64;
#define K1ACC(J, A) { float4 wv = *(const float4*)(wrow + (J)*64 + chq*4); \
        A = fmaf(xv.x,wv.x, fmaf(xv.y,wv.y, fmaf(xv.z,wv.z, fmaf(xv.w,wv.w, A)))); }
        #pragma unroll
        for (int chq = 0; chq < 16; ++chq) {
            float4 xv = *(const float4*)(sm + K1_XIN + p*68 + chq*4);
            K1ACC(0,a0) K1ACC(1,a1) K1ACC(2,a2) K1ACC(3,a3)
            K1ACC(4,a4) K1ACC(5,a5) K1ACC(6,a6) K1ACC(7,a7)
        }
#undef K1ACC
    }

    if (q >= 2) {   // z quarters: store and done
        float* zw = z_g + (size_t)win*8192 + ((q-2)*64)*64 + p;
        zw[(og*8+0)*64]=a0; zw[(og*8+1)*64]=a1; zw[(og*8+2)*64]=a2; zw[(og*8+3)*64]=a3;
        zw[(og*8+4)*64]=a4; zw[(og*8+5)*64]=a5; zw[(og*8+6)*64]=a6; zw[(og*8+7)*64]=a7;
        return;
    }

    // xc quarters: park in XCP[dloc][65]
    {
        float* xp = sm + K1_XCP + og*8*65 + p;
        xp[0]=a0; xp[65]=a1; xp[130]=a2; xp[195]=a3;
        xp[260]=a4; xp[325]=a5; xp[390]=a6; xp[455]=a7;
    }
    __syncthreads();

    // depthwise 3x3 conv + silu -> XOUT[p][68]
    {
        const int dloc = t & 63, qq = t >> 6;
        const int dg = q*64 + dloc;
        const float* cwp = conv_w + dg*9;
        const float c0=cwp[0],c1=cwp[1],c2=cwp[2],c3=cwp[3],c4=cwp[4],
                    c5=cwp[5],c6=cwp[6],c7=cwp[7],c8=cwp[8];
        const float cb = conv_b[dg];
        const float* xc = sm + K1_XCP + dloc*65;
        #pragma unroll
        for (int jj = 0; jj < 8; ++jj) {
            const int px = qq*8 + jj;
            const int r = px >> 3, c = px & 7;
            float a = cb;
            if (r > 0) {
                if (c > 0) a = fmaf(xc[px-9], c0, a);
                a = fmaf(xc[px-8], c1, a);
                if (c < 7) a = fmaf(xc[px-7], c2, a);
            }
            if (c > 0) a = fmaf(xc[px-1], c3, a);
            a = fmaf(xc[px], c4, a);
            if (c < 7) a = fmaf(xc[px+1], c5, a);
            if (r < 7) {
                if (c > 0) a = fmaf(xc[px+7], c6, a);
                a = fmaf(xc[px+8], c7, a);
                if (c < 7) a = fmaf(xc[px+9], c8, a);
            }
            sm[K1_XOUT + px*68 + dloc] = a / (1.f + __expf(-a));
        }
    }
    __syncthreads();

    // store xct (coalesced)
    {
        float* dst = xct_g + (size_t)win*8192 + q*64;
        #pragma unroll
        for (int i = 0; i < 2; ++i) {
            const int idx4 = i*512 + t;
            const int pp = idx4 >> 4, dg = idx4 & 15;
            float4 v = *(const float4*)(sm + K1_XOUT + pp*68 + dg*4);
            *(float4*)(dst + pp*128 + dg*4) = v;
        }
    }
}

// ================= K2: x_proj GEMM, one (win,k) per block; all operands in LDS =================
// LDS floats: XT[64p][64] swz @0 (4096) ; WL[36][64] @4096 (2304) ; XDOUT[64l][37] @6400 (2368)
#define K2_WL 4096
#define K2_XD 6400
#define K2_SMEM 8768

__global__ __launch_bounds__(256, 4)
void k2_xproj(const float* __restrict__ xct_g,
              const float* __restrict__ x_proj_w,
              float* __restrict__ xdbl_g)   // [win][4k][64l][36]
{
    __shared__ float sm[K2_SMEM];
    const int t = threadIdx.x;
    const int win = blockIdx.x >> 2, k = blockIdx.x & 3;
    const int p = t & 63, jg = t >> 6;
    float a0=0,a1=0,a2=0,a3=0,a4=0,a5=0,a6=0,a7=0,a8=0;

    for (int h = 0; h < 2; ++h) {
        __syncthreads();
        // stage XT half (swizzled granules)
        #pragma unroll
        for (int i = 0; i < 4; ++i) {
            const int idx4 = i*256 + t;
            const int pp = idx4 >> 4, dg = idx4 & 15;
            float4 v = *(const float4*)(xct_g + (size_t)win*8192 + pp*128 + h*64 + dg*4);
            *(float4*)(sm + pp*64 + ((dg ^ (pp&7))<<2)) = v;
        }
        // stage W half: 36 rows x 64 cols (linear; inner-loop reads are wave-uniform broadcasts)
        #pragma unroll
        for (int i = 0; i < 3; ++i) {
            const int idx4 = i*256 + t;
            if (idx4 < 576) {
                const int r = idx4 >> 4, dg = idx4 & 15;
                float4 v = *(const float4*)(x_proj_w + (size_t)(k*36 + r)*128 + h*64 + dg*4);
                *(float4*)(sm + K2_WL + r*64 + dg*4) = v;
            }
        }
        __syncthreads();
        const float* wb = sm + K2_WL + jg*9*64;
#define K2ACC(J, A) { float4 wv = *(const float4*)(wb + (J)*64 + dg*4); \
        A = fmaf(xv.x,wv.x, fmaf(xv.y,wv.y, fmaf(xv.z,wv.z, fmaf(xv.w,wv.w, A)))); }
        #pragma unroll
        for (int dg = 0; dg < 16; ++dg) {
            float4 xv = *(const float4*)(sm + p*64 + ((dg ^ (p&7))<<2));
            K2ACC(0,a0) K2ACC(1,a1) K2ACC(2,a2) K2ACC(3,a3) K2ACC(4,a4)
            K2ACC(5,a5) K2ACC(6,a6) K2ACC(7,a7) K2ACC(8,a8)
        }
#undef K2ACC
    }
    __syncthreads();

    // scatter into LDS in scan order (pad-37 rows)
    {
        const int l = (k==0) ? p : (k==1) ? transp(p) : (k==2) ? (63-p) : (63 - transp(p));
        float* dp = sm + K2_XD + l*37 + jg*9;
        dp[0]=a0; dp[1]=a1; dp[2]=a2; dp[3]=a3; dp[4]=a4;
        dp[5]=a5; dp[6]=a6; dp[7]=a7; dp[8]=a8;
    }
    __syncthreads();

    // coalesced linear store: [64l][36]
    {
        float* dst = xdbl_g + ((size_t)win*4 + k)*2304;
        #pragma unroll
        for (int i = 0; i < 9; ++i) {
            const int idx = i*256 + t;
            const int l2 = idx / 36, c = idx - l2*36;
            dst[idx] = sm[K2_XD + l2*37 + c];
        }
    }
}

// ================= K3: scan + merge + LN + gate + out_proj =================
#define K3_XD 0        // [4k][64l][36] = 9216
#define K3_YM 9216     // [128d][65]    = 8320
#define K3_MU 17536
#define K3_RS 17600
#define K3_SMEM 17664

__global__ __launch_bounds__(512, 4)
void k3_scan(const float* __restrict__ xct_g,
             const float* __restrict__ z_g,
             const float* __restrict__ xdbl_g,
             const float* __restrict__ dt_projs_w,
             const float* __restrict__ dt_projs_b,
             const float* __restrict__ A_logs,
             const float* __restrict__ Ds,
             const float* __restrict__ ln_g,
             const float* __restrict__ ln_b,
             const float* __restrict__ out_proj_w,
             float* __restrict__ out)
{
    __shared__ float sm[K3_SMEM];
    const int t = threadIdx.x;
    const int win = blockIdx.x;

    // stage xdbl into LDS; zero YM
    #pragma unroll
    for (int i = 0; i < 5; ++i) {
        const int idx4 = i*512 + t;
        if (idx4 < 2304) {
            float4 v = *(const float4*)(xdbl_g + (size_t)win*9216 + idx4*4);
            *(float4*)(sm + K3_XD + idx4*4) = v;
        }
    }
    for (int i = t; i < 8320; i += 512) sm[K3_YM + i] = 0.f;
    __syncthreads();

    // ---- scan: thread = (k,d), 16 states each ----
    {
        const int k = t >> 7, d = t & 127;
        const int kd = t;
        const float* alp = A_logs + kd*16;
        const float A0 = -__expf(alp[0]);
        bool fast = true;
        #pragma unroll
        for (int s = 1; s < 16; ++s) {
            float a = -__expf(alp[s]);
            fast = fast && (fabsf(a - (float)(s+1)*A0) <= 1e-4f * fabsf(a));
        }
        const float4 wv = *(const float4*)(dt_projs_w + kd*4);
        const float dtb = dt_projs_b[kd];
        const float Dv  = Ds[kd];
        float h0=0,h1=0,h2=0,h3=0,h4=0,h5=0,h6=0,h7=0,
              h8=0,h9=0,h10=0,h11=0,h12=0,h13=0,h14=0,h15=0;
        const float* XDk = sm + K3_XD + k*2304;
        const float* ub = xct_g + (size_t)win*8192 + d;

#define HSTEP(I, E, BC, CC) { h##I = fmaf(h##I, (E), dtu*(BC)); y = fmaf(h##I, (CC), y); }

        if (fast) {
            for (int l = 0; l < 64; ++l) {
                const float* row = XDk + l*36;
                float4 d4 = *(const float4*)(row);
                float4 b0 = *(const float4*)(row+4),  b1 = *(const float4*)(row+8);
                float4 b2 = *(const float4*)(row+12), b3 = *(const float4*)(row+16);
                float4 c0 = *(const float4*)(row+20), c1 = *(const float4*)(row+24);
                float4 c2 = *(const float4*)(row+28), c3 = *(const float4*)(row+32);
                float dtraw = dtb + wv.x*d4.x + wv.y*d4.y + wv.z*d4.z + wv.w*d4.w;
                float dt = (dtraw > 20.f) ? dtraw : __logf(1.f + __expf(dtraw));
                const int lr = 63 - l;
                const int p = (k==0)?l : (k==1)?transp(l) : (k==2)?lr : transp(lr);
                const float u = ub[p*128];
                const float dtu = dt * u;
                const float r  = __expf(dt * A0);
                const float r2 = r*r, r4 = r2*r2, r8 = r4*r4;
                const float e3 = r2*r, e5 = r4*r, e6 = r4*r2, e7 = r4*e3;
                const float e9 = r8*r, e10 = r8*r2, e11 = r8*e3, e12 = r8*r4;
                const float e13 = r8*e5, e14 = r8*e6, e15 = r8*e7, e16 = r8*r8;
                float y = Dv * u;
                HSTEP(0,  r,   b0.x, c0.x)  HSTEP(1,  r2,  b0.y, c0.y)
                HSTEP(2,  e3,  b0.z, c0.z)  HSTEP(3,  r4,  b0.w, c0.w)
                HSTEP(4,  e5,  b1.x, c1.x)  HSTEP(5,  e6,  b1.y, c1.y)
                HSTEP(6,  e7,  b1.z, c1.z)  HSTEP(7,  r8,  b1.w, c1.w)
                HSTEP(8,  e9,  b2.x, c2.x)  HSTEP(9,  e10, b2.y, c2.y)
                HSTEP(10, e11, b2.z, c2.z)  HSTEP(11, e12, b2.w, c2.w)
                HSTEP(12, e13, b3.x, c3.x)  HSTEP(13, e14, b3.y, c3.y)
                HSTEP(14, e15, b3.z, c3.z)  HSTEP(15, e16, b3.w, c3.w)
                atomicAdd(&sm[K3_YM + d*65 + p], y);
            }
        } else {
            const float A1=-__expf(alp[1]), A2=-__expf(alp[2]), A3=-__expf(alp[3]),
                        A4=-__expf(alp[4]), A5=-__expf(alp[5]), A6=-__expf(alp[6]),
                        A7=-__expf(alp[7]), A8=-__expf(alp[8]), A9=-__expf(alp[9]),
                        A10=-__expf(alp[10]), A11=-__expf(alp[11]), A12=-__expf(alp[12]),
                        A13=-__expf(alp[13]), A14=-__expf(alp[14]), A15=-__expf(alp[15]);
            for (int l = 0; l < 64; ++l) {
                const float* row = XDk + l*36;
                float4 d4 = *(const float4*)(row);
                float4 b0 = *(const float4*)(row+4),  b1 = *(const float4*)(row+8);
                float4 b2 = *(const float4*)(row+12), b3 = *(const float4*)(row+16);
                float4 c0 = *(const float4*)(row+20), c1 = *(const float4*)(row+24);
                float4 c2 = *(const float4*)(row+28), c3 = *(const float4*)(row+32);
                float dtraw = dtb + wv.x*d4.x + wv.y*d4.y + wv.z*d4.z + wv.w*d4.w;
                float dt = (dtraw > 20.f) ? dtraw : __logf(1.f + __expf(dtraw));
                const int lr = 63 - l;
                const int p = (k==0)?l : (k==1)?transp(l) : (k==2)?lr : transp(lr);
                const float u = ub[p*128];
                const float dtu = dt * u;
                float y = Dv * u;
                HSTEP(0,  __expf(dt*A0),  b0.x, c0.x)  HSTEP(1,  __expf(dt*A1),  b0.y, c0.y)
                HSTEP(2,  __expf(dt*A2),  b0.z, c0.z)  HSTEP(3,  __expf(dt*A3),  b0.w, c0.w)
                HSTEP(4,  __expf(dt*A4),  b1.x, c1.x)  HSTEP(5,  __expf(dt*A5),  b1.y, c1.y)
                HSTEP(6,  __expf(dt*A6),  b1.z, c1.z)  HSTEP(7,  __expf(dt*A7),  b1.w, c1.w)
                HSTEP(8,  __expf(dt*A8),  b2.x, c2.x)  HSTEP(9,  __expf(dt*A9),  b2.y, c2.y)
                HSTEP(10, __expf(dt*A10), b2.z, c2.z)  HSTEP(11, __expf(dt*A11), b2.w, c2.w)
                HSTEP(12, __expf(dt*A12), b3.x, c3.x)  HSTEP(13, __expf(dt*A13), b3.y, c3.y)
                HSTEP(14, __expf(dt*A14), b3.z, c3.z)  HSTEP(15, __expf(dt*A15), b3.w, c3.w)
                atomicAdd(&sm[K3_YM + d*65 + p], y);
            }
        }
#undef HSTEP
    }
    __syncthreads();

    // ---- LN stats: 8 lanes per pixel ----
    {
        const int px = t >> 3, j = t & 7;
        float s1 = 0.f, s2 = 0.f;
        #pragma unroll
        for (int i = 0; i < 16; ++i) {
            float v = sm[K3_YM + (j*16 + i)*65 + px];
            s1 += v; s2 += v*v;
        }
        s1 += __shfl_xor(s1,1); s2 += __shfl_xor(s2,1);
        s1 += __shfl_xor(s1,2); s2 += __shfl_xor(s2,2);
        s1 += __shfl_xor(s1,4); s2 += __shfl_xor(s2,4);
        if (j == 0) {
            float mu  = s1 * 0.0078125f;
            float var = s2 * 0.0078125f - mu*mu;
            sm[K3_MU + px] = mu;
            sm[K3_RS + px] = rsqrtf(var + 1e-5f);
        }
    }
    __syncthreads();

    // ---- yhat = LN(y) * silu(z), in place ----
    {
        const int p = t & 63, dblk = (t >> 6) * 16;
        const float mu = sm[K3_MU + p], rs = sm[K3_RS + p];
        const float* zb = z_g + (size_t)win*8192 + p;
        #pragma unroll
        for (int i = 0; i < 16; ++i) {
            const int d = dblk + i;
            float yv = sm[K3_YM + d*65 + p];
            float yh = (yv - mu)*rs*ln_g[d] + ln_b[d];
            float zv = zb[d*64];
            sm[K3_YM + d*65 + p] = yh * (zv / (1.f + __expf(-zv)));
        }
    }
    __syncthreads();

    // ---- out_proj: thread = (p, m-octet) ----
    {
        const int p = t & 63, m0 = (t >> 6) * 8;
        float o0=0,o1=0,o2=0,o3=0,o4=0,o5=0,o6=0,o7=0;
#define OACC(J, O) { float4 wq = *(const float4*)(out_proj_w + (m0+(J))*128 + dq*4); \
        O = fmaf(y0,wq.x, fmaf(y1,wq.y, fmaf(y2,wq.z, fmaf(y3,wq.w, O)))); }
        #pragma unroll
        for (int dq = 0; dq < 32; ++dq) {
            float y0 = sm[K3_YM + (dq*4+0)*65 + p];
            float y1 = sm[K3_YM + (dq*4+1)*65 + p];
            float y2 = sm[K3_YM + (dq*4+2)*65 + p];
            float y3 = sm[K3_YM + (dq*4+3)*65 + p];
            OACC(0,o0) OACC(1,o1) OACC(2,o2) OACC(3,o3)
            OACC(4,o4) OACC(5,o5) OACC(6,o6) OACC(7,o7)
        }
#undef OACC
        const int b = win >> 8, ih = (win>>4)&15, iw = win&15;
        float* op = out + ((size_t)b*64)*L_HW + (ih*8 + (p>>3))*128 + iw*8 + (p&7);
        op[(size_t)(m0+0)*L_HW]=o0; op[(size_t)(m0+1)*L_HW]=o1;
        op[(size_t)(m0+2)*L_HW]=o2; op[(size_t)(m0+3)*L_HW]=o3;
        op[(size_t)(m0+4)*L_HW]=o4; op[(size_t)(m0+5)*L_HW]=o5;
        op[(size_t)(m0+6)*L_HW]=o6; op[(size_t)(m0+7)*L_HW]=o7;
    }
}

extern "C" void kernel_launch(void* const* d_in, const int* in_sizes, int n_in,
                              void* d_out, int out_size, void* d_ws, size_t ws_size,
                              hipStream_t stream) {
    const float* x          = (const float*)d_in[0];
    const float* in_proj_w  = (const float*)d_in[1];
    const float* conv_w     = (const float*)d_in[2];
    const float* conv_b     = (const float*)d_in[3];
    const float* x_proj_w   = (const float*)d_in[4];
    const float* dt_projs_w = (const float*)d_in[5];
    const float* dt_projs_b = (const float*)d_in[6];
    const float* A_logs     = (const float*)d_in[7];
    const float* Ds         = (const float*)d_in[8];
    const float* ln_g       = (const float*)d_in[9];
    const float* ln_b       = (const float*)d_in[10];
    const float* out_proj_w = (const float*)d_in[11];
    float* out = (float*)d_out;

    float* xct  = (float*)d_ws;            // 512*8192
    float* zb   = xct + 4194304;           // 512*8192
    float* xdbl = zb  + 4194304;           // 512*4*64*36

    k1_gemm<<<dim3(2048), dim3(512), 0, stream>>>(x, in_proj_w, conv_w, conv_b, xct, zb);
    k2_xproj<<<dim3(2048), dim3(256), 0, stream>>>(xct, x_proj_w, xdbl);
    k3_scan<<<dim3(512), dim3(512), 0, stream>>>(
        xct, zb, xdbl, dt_projs_w, dt_projs_b, A_logs, Ds, ln_g, ln_b,
        out_proj_w, out);
}

// Round 8
// 161.129 us; speedup vs baseline: 8.0057x; 1.2951x over previous
//
#include <hip/hip_runtime.h>

#define L_HW (128*128)

__device__ __forceinline__ int transp(int p){ return ((p&7)<<3)|(p>>3); }

// ================= K1: in_proj GEMM quarters (+conv+silu for xc) =================
#define K1_XIN  0
#define K1_WBUF 4352
#define K1_XCP  8448
#define K1_XOUT 0
#define K1_SMEM 12608

__global__ __launch_bounds__(512, 4)
void k1_gemm(const float* __restrict__ x,
             const float* __restrict__ in_proj_w,
             const float* __restrict__ conv_w,
             const float* __restrict__ conv_b,
             float* __restrict__ xct_g,   // [win][64p][128d]
             float* __restrict__ z_g)     // [win][128d][64p]
{
    __shared__ float sm[K1_SMEM];
    const int t = threadIdx.x;
    const int win = blockIdx.x >> 2, q = blockIdx.x & 3;
    const int b = win >> 8, ih = (win >> 4) & 15, iw = win & 15;
    const float* xwin = x + ((size_t)b*64)*L_HW + ih*8*128 + iw*8;

    {
        const int ch = t >> 3, r = t & 7;
        const float* src = xwin + (size_t)ch*L_HW + r*128;
        float4 v0 = *(const float4*)(src);
        float4 v1 = *(const float4*)(src + 4);
        float* dst = sm + K1_XIN + ch;
        const int p0 = r*8;
        dst[(p0+0)*68]=v0.x; dst[(p0+1)*68]=v0.y; dst[(p0+2)*68]=v0.z; dst[(p0+3)*68]=v0.w;
        dst[(p0+4)*68]=v1.x; dst[(p0+5)*68]=v1.y; dst[(p0+6)*68]=v1.z; dst[(p0+7)*68]=v1.w;
    }
    {
        const float* wsrc = in_proj_w + q*4096;
        *(float4*)(sm + K1_WBUF + t*4)        = *(const float4*)(wsrc + t*4);
        *(float4*)(sm + K1_WBUF + (t+512)*4)  = *(const float4*)(wsrc + (t+512)*4);
    }
    __syncthreads();

    const int p = t & 63, og = t >> 6;
    float a0=0,a1=0,a2=0,a3=0,a4=0,a5=0,a6=0,a7=0;
    {
        const float* wrow = sm + K1_WBUF + og*8*64;
#define K1ACC(J, A) { float4 wv = *(const float4*)(wrow + (J)*64 + chq*4); \
        A = fmaf(xv.x,wv.x, fmaf(xv.y,wv.y, fmaf(xv.z,wv.z, fmaf(xv.w,wv.w, A)))); }
        #pragma unroll
        for (int chq = 0; chq < 16; ++chq) {
            float4 xv = *(const float4*)(sm + K1_XIN + p*68 + chq*4);
            K1ACC(0,a0) K1ACC(1,a1) K1ACC(2,a2) K1ACC(3,a3)
            K1ACC(4,a4) K1ACC(5,a5) K1ACC(6,a6) K1ACC(7,a7)
        }
#undef K1ACC
    }

    if (q >= 2) {
        float* zw = z_g + (size_t)win*8192 + ((q-2)*64)*64 + p;
        zw[(og*8+0)*64]=a0; zw[(og*8+1)*64]=a1; zw[(og*8+2)*64]=a2; zw[(og*8+3)*64]=a3;
        zw[(og*8+4)*64]=a4; zw[(og*8+5)*64]=a5; zw[(og*8+6)*64]=a6; zw[(og*8+7)*64]=a7;
        return;
    }

    {
        float* xp = sm + K1_XCP + og*8*65 + p;
        xp[0]=a0; xp[65]=a1; xp[130]=a2; xp[195]=a3;
        xp[260]=a4; xp[325]=a5; xp[390]=a6; xp[455]=a7;
    }
    __syncthreads();

    {
        const int dloc = t & 63, qq = t >> 6;
        const int dg = q*64 + dloc;
        const float* cwp = conv_w + dg*9;
        const float c0=cwp[0],c1=cwp[1],c2=cwp[2],c3=cwp[3],c4=cwp[4],
                    c5=cwp[5],c6=cwp[6],c7=cwp[7],c8=cwp[8];
        const float cb = conv_b[dg];
        const float* xc = sm + K1_XCP + dloc*65;
        #pragma unroll
        for (int jj = 0; jj < 8; ++jj) {
            const int px = qq*8 + jj;
            const int r = px >> 3, c = px & 7;
            float a = cb;
            if (r > 0) {
                if (c > 0) a = fmaf(xc[px-9], c0, a);
                a = fmaf(xc[px-8], c1, a);
                if (c < 7) a = fmaf(xc[px-7], c2, a);
            }
            if (c > 0) a = fmaf(xc[px-1], c3, a);
            a = fmaf(xc[px], c4, a);
            if (c < 7) a = fmaf(xc[px+1], c5, a);
            if (r < 7) {
                if (c > 0) a = fmaf(xc[px+7], c6, a);
                a = fmaf(xc[px+8], c7, a);
                if (c < 7) a = fmaf(xc[px+9], c8, a);
            }
            sm[K1_XOUT + px*68 + dloc] = a / (1.f + __expf(-a));
        }
    }
    __syncthreads();

    {
        float* dst = xct_g + (size_t)win*8192 + q*64;
        #pragma unroll
        for (int i = 0; i < 2; ++i) {
            const int idx4 = i*512 + t;
            const int pp = idx4 >> 4, dg = idx4 & 15;
            float4 v = *(const float4*)(sm + K1_XOUT + pp*68 + dg*4);
            *(float4*)(dst + pp*128 + dg*4) = v;
        }
    }
}

// ================= K2: x_proj GEMM (operands in LDS) =================
#define K2_WL 4096
#define K2_XD 6400
#define K2_SMEM 8768

__global__ __launch_bounds__(256, 4)
void k2_xproj(const float* __restrict__ xct_g,
              const float* __restrict__ x_proj_w,
              float* __restrict__ xdbl_g)   // [win][4k][64l][36]
{
    __shared__ float sm[K2_SMEM];
    const int t = threadIdx.x;
    const int win = blockIdx.x >> 2, k = blockIdx.x & 3;
    const int p = t & 63, jg = t >> 6;
    float a0=0,a1=0,a2=0,a3=0,a4=0,a5=0,a6=0,a7=0,a8=0;

    for (int h = 0; h < 2; ++h) {
        __syncthreads();
        #pragma unroll
        for (int i = 0; i < 4; ++i) {
            const int idx4 = i*256 + t;
            const int pp = idx4 >> 4, dg = idx4 & 15;
            float4 v = *(const float4*)(xct_g + (size_t)win*8192 + pp*128 + h*64 + dg*4);
            *(float4*)(sm + pp*64 + ((dg ^ (pp&7))<<2)) = v;
        }
        #pragma unroll
        for (int i = 0; i < 3; ++i) {
            const int idx4 = i*256 + t;
            if (idx4 < 576) {
                const int r = idx4 >> 4, dg = idx4 & 15;
                float4 v = *(const float4*)(x_proj_w + (size_t)(k*36 + r)*128 + h*64 + dg*4);
                *(float4*)(sm + K2_WL + r*64 + dg*4) = v;
            }
        }
        __syncthreads();
        const float* wb = sm + K2_WL + jg*9*64;
#define K2ACC(J, A) { float4 wv = *(const float4*)(wb + (J)*64 + dg*4); \
        A = fmaf(xv.x,wv.x, fmaf(xv.y,wv.y, fmaf(xv.z,wv.z, fmaf(xv.w,wv.w, A)))); }
        #pragma unroll
        for (int dg = 0; dg < 16; ++dg) {
            float4 xv = *(const float4*)(sm + p*64 + ((dg ^ (p&7))<<2));
            K2ACC(0,a0) K2ACC(1,a1) K2ACC(2,a2) K2ACC(3,a3) K2ACC(4,a4)
            K2ACC(5,a5) K2ACC(6,a6) K2ACC(7,a7) K2ACC(8,a8)
        }
#undef K2ACC
    }
    __syncthreads();

    {
        const int l = (k==0) ? p : (k==1) ? transp(p) : (k==2) ? (63-p) : (63 - transp(p));
        float* dp = sm + K2_XD + l*37 + jg*9;
        dp[0]=a0; dp[1]=a1; dp[2]=a2; dp[3]=a3; dp[4]=a4;
        dp[5]=a5; dp[6]=a6; dp[7]=a7; dp[8]=a8;
    }
    __syncthreads();

    {
        float* dst = xdbl_g + ((size_t)win*4 + k)*2304;
        #pragma unroll
        for (int i = 0; i < 9; ++i) {
            const int idx = i*256 + t;
            const int l2 = idx / 36, c = idx - l2*36;
            dst[idx] = sm[K2_XD + l2*37 + c];
        }
    }
}

// ================= shared scan body macros =================
#define HSTEP(I, E, BC, CC) { h##I = fmaf(h##I, (E), dtu*(BC)); y = fmaf(h##I, (CC), y); }

// ================= K3a: scan only, no atomics, y -> global =================
__global__ __launch_bounds__(512, 4)
void k3a_scan(const float* __restrict__ xct_g,
              const float* __restrict__ xdbl_g,
              const float* __restrict__ dt_projs_w,
              const float* __restrict__ dt_projs_b,
              const float* __restrict__ A_logs,
              float* __restrict__ y_g)     // [win][4k][64l][128d]
{
    __shared__ float sm[9216];
    const int t = threadIdx.x;
    const int win = blockIdx.x;

    #pragma unroll
    for (int i = 0; i < 5; ++i) {
        const int idx4 = i*512 + t;
        if (idx4 < 2304) {
            float4 v = *(const float4*)(xdbl_g + (size_t)win*9216 + idx4*4);
            *(float4*)(sm + idx4*4) = v;
        }
    }
    __syncthreads();

    const int k = t >> 7, d = t & 127;
    const int kd = t;
    const float* alp = A_logs + kd*16;
    const float A0 = -__expf(alp[0]);
    bool fast = true;
    #pragma unroll
    for (int s = 1; s < 16; ++s) {
        float a = -__expf(alp[s]);
        fast = fast && (fabsf(a - (float)(s+1)*A0) <= 1e-4f * fabsf(a));
    }
    const float4 wv = *(const float4*)(dt_projs_w + kd*4);
    const float dtb = dt_projs_b[kd];
    float h0=0,h1=0,h2=0,h3=0,h4=0,h5=0,h6=0,h7=0,
          h8=0,h9=0,h10=0,h11=0,h12=0,h13=0,h14=0,h15=0;
    const float* XDk = sm + k*2304;
    const float* ub = xct_g + (size_t)win*8192 + d;
    float* yw = y_g + ((size_t)win*4 + k)*8192 + d;

    if (fast) {
        for (int l = 0; l < 64; ++l) {
            const float* row = XDk + l*36;
            float4 d4 = *(const float4*)(row);
            float4 b0 = *(const float4*)(row+4),  b1 = *(const float4*)(row+8);
            float4 b2 = *(const float4*)(row+12), b3 = *(const float4*)(row+16);
            float4 c0 = *(const float4*)(row+20), c1 = *(const float4*)(row+24);
            float4 c2 = *(const float4*)(row+28), c3 = *(const float4*)(row+32);
            float dtraw = dtb + wv.x*d4.x + wv.y*d4.y + wv.z*d4.z + wv.w*d4.w;
            float dt = (dtraw > 20.f) ? dtraw : __logf(1.f + __expf(dtraw));
            const int lr = 63 - l;
            const int p = (k==0)?l : (k==1)?transp(l) : (k==2)?lr : transp(lr);
            const float u = ub[p*128];
            const float dtu = dt * u;
            const float r  = __expf(dt * A0);
            const float r2 = r*r, r4 = r2*r2, r8 = r4*r4;
            const float e3 = r2*r, e5 = r4*r, e6 = r4*r2, e7 = r4*e3;
            const float e9 = r8*r, e10 = r8*r2, e11 = r8*e3, e12 = r8*r4;
            const float e13 = r8*e5, e14 = r8*e6, e15 = r8*e7, e16 = r8*r8;
            float y = 0.f;
            HSTEP(0,  r,   b0.x, c0.x)  HSTEP(1,  r2,  b0.y, c0.y)
            HSTEP(2,  e3,  b0.z, c0.z)  HSTEP(3,  r4,  b0.w, c0.w)
            HSTEP(4,  e5,  b1.x, c1.x)  HSTEP(5,  e6,  b1.y, c1.y)
            HSTEP(6,  e7,  b1.z, c1.z)  HSTEP(7,  r8,  b1.w, c1.w)
            HSTEP(8,  e9,  b2.x, c2.x)  HSTEP(9,  e10, b2.y, c2.y)
            HSTEP(10, e11, b2.z, c2.z)  HSTEP(11, e12, b2.w, c2.w)
            HSTEP(12, e13, b3.x, c3.x)  HSTEP(13, e14, b3.y, c3.y)
            HSTEP(14, e15, b3.z, c3.z)  HSTEP(15, e16, b3.w, c3.w)
            yw[l*128] = y;
        }
    } else {
        const float A1=-__expf(alp[1]), A2=-__expf(alp[2]), A3=-__expf(alp[3]),
                    A4=-__expf(alp[4]), A5=-__expf(alp[5]), A6=-__expf(alp[6]),
                    A7=-__expf(alp[7]), A8=-__expf(alp[8]), A9=-__expf(alp[9]),
                    A10=-__expf(alp[10]), A11=-__expf(alp[11]), A12=-__expf(alp[12]),
                    A13=-__expf(alp[13]), A14=-__expf(alp[14]), A15=-__expf(alp[15]);
        for (int l = 0; l < 64; ++l) {
            const float* row = XDk + l*36;
            float4 d4 = *(const float4*)(row);
            float4 b0 = *(const float4*)(row+4),  b1 = *(const float4*)(row+8);
            float4 b2 = *(const float4*)(row+12), b3 = *(const float4*)(row+16);
            float4 c0 = *(const float4*)(row+20), c1 = *(const float4*)(row+24);
            float4 c2 = *(const float4*)(row+28), c3 = *(const float4*)(row+32);
            float dtraw = dtb + wv.x*d4.x + wv.y*d4.y + wv.z*d4.z + wv.w*d4.w;
            float dt = (dtraw > 20.f) ? dtraw : __logf(1.f + __expf(dtraw));
            const int lr = 63 - l;
            const int p = (k==0)?l : (k==1)?transp(l) : (k==2)?lr : transp(lr);
            const float u = ub[p*128];
            const float dtu = dt * u;
            float y = 0.f;
            HSTEP(0,  __expf(dt*A0),  b0.x, c0.x)  HSTEP(1,  __expf(dt*A1),  b0.y, c0.y)
            HSTEP(2,  __expf(dt*A2),  b0.z, c0.z)  HSTEP(3,  __expf(dt*A3),  b0.w, c0.w)
            HSTEP(4,  __expf(dt*A4),  b1.x, c1.x)  HSTEP(5,  __expf(dt*A5),  b1.y, c1.y)
            HSTEP(6,  __expf(dt*A6),  b1.z, c1.z)  HSTEP(7,  __expf(dt*A7),  b1.w, c1.w)
            HSTEP(8,  __expf(dt*A8),  b2.x, c2.x)  HSTEP(9,  __expf(dt*A9),  b2.y, c2.y)
            HSTEP(10, __expf(dt*A10), b2.z, c2.z)  HSTEP(11, __expf(dt*A11), b2.w, c2.w)
            HSTEP(12, __expf(dt*A12), b3.x, c3.x)  HSTEP(13, __expf(dt*A13), b3.y, c3.y)
            HSTEP(14, __expf(dt*A14), b3.z, c3.z)  HSTEP(15, __expf(dt*A15), b3.w, c3.w)
            yw[l*128] = y;
        }
    }
}

// ================= K3b: gather-merge + LN + gate + out_proj =================
#define KB_YM 0
#define KB_MU 8320
#define KB_RS 8384
#define KB_SMEM 8448

__global__ __launch_bounds__(512, 4)
void k3b_post(const float* __restrict__ y_g,
              const float* __restrict__ xct_g,
              const float* __restrict__ z_g,
              const float* __restrict__ Ds,
              const float* __restrict__ ln_g,
              const float* __restrict__ ln_b,
              const float* __restrict__ out_proj_w,
              float* __restrict__ out)
{
    __shared__ float sm[KB_SMEM];
    const int t = threadIdx.x;
    const int win = blockIdx.x;

    // gather-merge: thread = (d2, p-quarter)
    {
        const int d2 = t & 127, pq = t >> 7;
        const float Dsum = Ds[d2] + Ds[128+d2] + Ds[256+d2] + Ds[384+d2];
        const float* yg0 = y_g + ((size_t)win*4 + 0)*8192 + d2;
        const float* yg1 = y_g + ((size_t)win*4 + 1)*8192 + d2;
        const float* yg2 = y_g + ((size_t)win*4 + 2)*8192 + d2;
        const float* yg3 = y_g + ((size_t)win*4 + 3)*8192 + d2;
        const float* uc  = xct_g + (size_t)win*8192 + d2;
        #pragma unroll
        for (int i = 0; i < 16; ++i) {
            const int p = pq*16 + i;
            const int tp = transp(p);
            float v = yg0[p*128] + yg1[tp*128] + yg2[(63-p)*128] + yg3[(63-tp)*128]
                    + Dsum * uc[p*128];
            sm[KB_YM + d2*65 + p] = v;
        }
    }
    __syncthreads();

    // LN stats: 8 lanes per pixel
    {
        const int px = t >> 3, j = t & 7;
        float s1 = 0.f, s2 = 0.f;
        #pragma unroll
        for (int i = 0; i < 16; ++i) {
            float v = sm[KB_YM + (j*16 + i)*65 + px];
            s1 += v; s2 += v*v;
        }
        s1 += __shfl_xor(s1,1); s2 += __shfl_xor(s2,1);
        s1 += __shfl_xor(s1,2); s2 += __shfl_xor(s2,2);
        s1 += __shfl_xor(s1,4); s2 += __shfl_xor(s2,4);
        if (j == 0) {
            float mu  = s1 * 0.0078125f;
            float var = s2 * 0.0078125f - mu*mu;
            sm[KB_MU + px] = mu;
            sm[KB_RS + px] = rsqrtf(var + 1e-5f);
        }
    }
    __syncthreads();

    // yhat = LN(y) * silu(z)
    {
        const int p = t & 63, dblk = (t >> 6) * 16;
        const float mu = sm[KB_MU + p], rs = sm[KB_RS + p];
        const float* zb = z_g + (size_t)win*8192 + p;
        #pragma unroll
        for (int i = 0; i < 16; ++i) {
            const int d = dblk + i;
            float yv = sm[KB_YM + d*65 + p];
            float yh = (yv - mu)*rs*ln_g[d] + ln_b[d];
            float zv = zb[d*64];
            sm[KB_YM + d*65 + p] = yh * (zv / (1.f + __expf(-zv)));
        }
    }
    __syncthreads();

    // out_proj
    {
        const int p = t & 63, m0 = (t >> 6) * 8;
        float o0=0,o1=0,o2=0,o3=0,o4=0,o5=0,o6=0,o7=0;
#define OACC(J, O) { float4 wq = *(const float4*)(out_proj_w + (m0+(J))*128 + dq*4); \
        O = fmaf(y0,wq.x, fmaf(y1,wq.y, fmaf(y2,wq.z, fmaf(y3,wq.w, O)))); }
        #pragma unroll
        for (int dq = 0; dq < 32; ++dq) {
            float y0 = sm[KB_YM + (dq*4+0)*65 + p];
            float y1 = sm[KB_YM + (dq*4+1)*65 + p];
            float y2 = sm[KB_YM + (dq*4+2)*65 + p];
            float y3 = sm[KB_YM + (dq*4+3)*65 + p];
            OACC(0,o0) OACC(1,o1) OACC(2,o2) OACC(3,o3)
            OACC(4,o4) OACC(5,o5) OACC(6,o6) OACC(7,o7)
        }
#undef OACC
        const int b = win >> 8, ih = (win>>4)&15, iw = win&15;
        float* op = out + ((size_t)b*64)*L_HW + (ih*8 + (p>>3))*128 + iw*8 + (p&7);
        op[(size_t)(m0+0)*L_HW]=o0; op[(size_t)(m0+1)*L_HW]=o1;
        op[(size_t)(m0+2)*L_HW]=o2; op[(size_t)(m0+3)*L_HW]=o3;
        op[(size_t)(m0+4)*L_HW]=o4; op[(size_t)(m0+5)*L_HW]=o5;
        op[(size_t)(m0+6)*L_HW]=o6; op[(size_t)(m0+7)*L_HW]=o7;
    }
}

// ================= K3 fused fallback (R7 version, used if ws too small) =================
#define K3_XD 0
#define K3_YM 9216
#define K3_MU 17536
#define K3_RS 17600
#define K3_SMEM 17664

__global__ __launch_bounds__(512, 4)
void k3_fused(const float* __restrict__ xct_g,
              const float* __restrict__ z_g,
              const float* __restrict__ xdbl_g,
              const float* __restrict__ dt_projs_w,
              const float* __restrict__ dt_projs_b,
              const float* __restrict__ A_logs,
              const float* __restrict__ Ds,
              const float* __restrict__ ln_g,
              const float* __restrict__ ln_b,
              const float* __restrict__ out_proj_w,
              float* __restrict__ out)
{
    __shared__ float sm[K3_SMEM];
    const int t = threadIdx.x;
    const int win = blockIdx.x;

    #pragma unroll
    for (int i = 0; i < 5; ++i) {
        const int idx4 = i*512 + t;
        if (idx4 < 2304) {
            float4 v = *(const float4*)(xdbl_g + (size_t)win*9216 + idx4*4);
            *(float4*)(sm + K3_XD + idx4*4) = v;
        }
    }
    for (int i = t; i < 8320; i += 512) sm[K3_YM + i] = 0.f;
    __syncthreads();

    {
        const int k = t >> 7, d = t & 127;
        const int kd = t;
        const float* alp = A_logs + kd*16;
        const float A0 = -__expf(alp[0]);
        bool fast = true;
        #pragma unroll
        for (int s = 1; s < 16; ++s) {
            float a = -__expf(alp[s]);
            fast = fast && (fabsf(a - (float)(s+1)*A0) <= 1e-4f * fabsf(a));
        }
        const float4 wv = *(const float4*)(dt_projs_w + kd*4);
        const float dtb = dt_projs_b[kd];
        const float Dv  = Ds[kd];
        float h0=0,h1=0,h2=0,h3=0,h4=0,h5=0,h6=0,h7=0,
              h8=0,h9=0,h10=0,h11=0,h12=0,h13=0,h14=0,h15=0;
        const float* XDk = sm + K3_XD + k*2304;
        const float* ub = xct_g + (size_t)win*8192 + d;

        if (fast) {
            for (int l = 0; l < 64; ++l) {
                const float* row = XDk + l*36;
                float4 d4 = *(const float4*)(row);
                float4 b0 = *(const float4*)(row+4),  b1 = *(const float4*)(row+8);
                float4 b2 = *(const float4*)(row+12), b3 = *(const float4*)(row+16);
                float4 c0 = *(const float4*)(row+20), c1 = *(const float4*)(row+24);
                float4 c2 = *(const float4*)(row+28), c3 = *(const float4*)(row+32);
                float dtraw = dtb + wv.x*d4.x + wv.y*d4.y + wv.z*d4.z + wv.w*d4.w;
                float dt = (dtraw > 20.f) ? dtraw : __logf(1.f + __expf(dtraw));
                const int lr = 63 - l;
                const int p = (k==0)?l : (k==1)?transp(l) : (k==2)?lr : transp(lr);
                const float u = ub[p*128];
                const float dtu = dt * u;
                const float r  = __expf(dt * A0);
                const float r2 = r*r, r4 = r2*r2, r8 = r4*r4;
                const float e3 = r2*r, e5 = r4*r, e6 = r4*r2, e7 = r4*e3;
                const float e9 = r8*r, e10 = r8*r2, e11 = r8*e3, e12 = r8*r4;
                const float e13 = r8*e5, e14 = r8*e6, e15 = r8*e7, e16 = r8*r8;
                float y = Dv * u;
                HSTEP(0,  r,   b0.x, c0.x)  HSTEP(1,  r2,  b0.y, c0.y)
                HSTEP(2,  e3,  b0.z, c0.z)  HSTEP(3,  r4,  b0.w, c0.w)
                HSTEP(4,  e5,  b1.x, c1.x)  HSTEP(5,  e6,  b1.y, c1.y)
                HSTEP(6,  e7,  b1.z, c1.z)  HSTEP(7,  r8,  b1.w, c1.w)
                HSTEP(8,  e9,  b2.x, c2.x)  HSTEP(9,  e10, b2.y, c2.y)
                HSTEP(10, e11, b2.z, c2.z)  HSTEP(11, e12, b2.w, c2.w)
                HSTEP(12, e13, b3.x, c3.x)  HSTEP(13, e14, b3.y, c3.y)
                HSTEP(14, e15, b3.z, c3.z)  HSTEP(15, e16, b3.w, c3.w)
                atomicAdd(&sm[K3_YM + d*65 + p], y);
            }
        } else {
            const float A1=-__expf(alp[1]), A2=-__expf(alp[2]), A3=-__expf(alp[3]),
                        A4=-__expf(alp[4]), A5=-__expf(alp[5]), A6=-__expf(alp[6]),
                        A7=-__expf(alp[7]), A8=-__expf(alp[8]), A9=-__expf(alp[9]),
                        A10=-__expf(alp[10]), A11=-__expf(alp[11]), A12=-__expf(alp[12]),
                        A13=-__expf(alp[13]), A14=-__expf(alp[14]), A15=-__expf(alp[15]);
            for (int l = 0; l < 64; ++l) {
                const float* row = XDk + l*36;
                float4 d4 = *(const float4*)(row);
                float4 b0 = *(const float4*)(row+4),  b1 = *(const float4*)(row+8);
                float4 b2 = *(const float4*)(row+12), b3 = *(const float4*)(row+16);
                float4 c0 = *(const float4*)(row+20), c1 = *(const float4*)(row+24);
                float4 c2 = *(const float4*)(row+28), c3 = *(const float4*)(row+32);
                float dtraw = dtb + wv.x*d4.x + wv.y*d4.y + wv.z*d4.z + wv.w*d4.w;
                float dt = (dtraw > 20.f) ? dtraw : __logf(1.f + __expf(dtraw));
                const int lr = 63 - l;
                const int p = (k==0)?l : (k==1)?transp(l) : (k==2)?lr : transp(lr);
                const float u = ub[p*128];
                const float dtu = dt * u;
                float y = Dv * u;
                HSTEP(0,  __expf(dt*A0),  b0.x, c0.x)  HSTEP(1,  __expf(dt*A1),  b0.y, c0.y)
                HSTEP(2,  __expf(dt*A2),  b0.z, c0.z)  HSTEP(3,  __expf(dt*A3),  b0.w, c0.w)
                HSTEP(4,  __expf(dt*A4),  b1.x, c1.x)  HSTEP(5,  __expf(dt*A5),  b1.y, c1.y)
                HSTEP(6,  __expf(dt*A6),  b1.z, c1.z)  HSTEP(7,  __expf(dt*A7),  b1.w, c1.w)
                HSTEP(8,  __expf(dt*A8),  b2.x, c2.x)  HSTEP(9,  __expf(dt*A9),  b2.y, c2.y)
                HSTEP(10, __expf(dt*A10), b2.z, c2.z)  HSTEP(11, __expf(dt*A11), b2.w, c2.w)
                HSTEP(12, __expf(dt*A12), b3.x, c3.x)  HSTEP(13, __expf(dt*A13), b3.y, c3.y)
                HSTEP(14, __expf(dt*A14), b3.z, c3.z)  HSTEP(15, __expf(dt*A15), b3.w, c3.w)
                atomicAdd(&sm[K3_YM + d*65 + p], y);
            }
        }
    }
    __syncthreads();

    {
        const int px = t >> 3, j = t & 7;
        float s1 = 0.f, s2 = 0.f;
        #pragma unroll
        for (int i = 0; i < 16; ++i) {
            float v = sm[K3_YM + (j*16 + i)*65 + px];
            s1 += v; s2 += v*v;
        }
        s1 += __shfl_xor(s1,1); s2 += __shfl_xor(s2,1);
        s1 += __shfl_xor(s1,2); s2 += __shfl_xor(s2,2);
        s1 += __shfl_xor(s1,4); s2 += __shfl_xor(s2,4);
        if (j == 0) {
            float mu  = s1 * 0.0078125f;
            float var = s2 * 0.0078125f - mu*mu;
            sm[K3_MU + px] = mu;
            sm[K3_RS + px] = rsqrtf(var + 1e-5f);
        }
    }
    __syncthreads();

    {
        const int p = t & 63, dblk = (t >> 6) * 16;
        const float mu = sm[K3_MU + p], rs = sm[K3_RS + p];
        const float* zb = z_g + (size_t)win*8192 + p;
        #pragma unroll
        for (int i = 0; i < 16; ++i) {
            const int d = dblk + i;
            float yv = sm[K3_YM + d*65 + p];
            float yh = (yv - mu)*rs*ln_g[d] + ln_b[d];
            float zv = zb[d*64];
            sm[K3_YM + d*65 + p] = yh * (zv / (1.f + __expf(-zv)));
        }
    }
    __syncthreads();

    {
        const int p = t & 63, m0 = (t >> 6) * 8;
        float o0=0,o1=0,o2=0,o3=0,o4=0,o5=0,o6=0,o7=0;
#define OACC(J, O) { float4 wq = *(const float4*)(out_proj_w + (m0+(J))*128 + dq*4); \
        O = fmaf(y0,wq.x, fmaf(y1,wq.y, fmaf(y2,wq.z, fmaf(y3,wq.w, O)))); }
        #pragma unroll
        for (int dq = 0; dq < 32; ++dq) {
            float y0 = sm[K3_YM + (dq*4+0)*65 + p];
            float y1 = sm[K3_YM + (dq*4+1)*65 + p];
            float y2 = sm[K3_YM + (dq*4+2)*65 + p];
            float y3 = sm[K3_YM + (dq*4+3)*65 + p];
            OACC(0,o0) OACC(1,o1) OACC(2,o2) OACC(3,o3)
            OACC(4,o4) OACC(5,o5) OACC(6,o6) OACC(7,o7)
        }
#undef OACC
        const int b = win >> 8, ih = (win>>4)&15, iw = win&15;
        float* op = out + ((size_t)b*64)*L_HW + (ih*8 + (p>>3))*128 + iw*8 + (p&7);
        op[(size_t)(m0+0)*L_HW]=o0; op[(size_t)(m0+1)*L_HW]=o1;
        op[(size_t)(m0+2)*L_HW]=o2; op[(size_t)(m0+3)*L_HW]=o3;
        op[(size_t)(m0+4)*L_HW]=o4; op[(size_t)(m0+5)*L_HW]=o5;
        op[(size_t)(m0+6)*L_HW]=o6; op[(size_t)(m0+7)*L_HW]=o7;
    }
}
#undef HSTEP

extern "C" void kernel_launch(void* const* d_in, const int* in_sizes, int n_in,
                              void* d_out, int out_size, void* d_ws, size_t ws_size,
                              hipStream_t stream) {
    const float* x          = (const float*)d_in[0];
    const float* in_proj_w  = (const float*)d_in[1];
    const float* conv_w     = (const float*)d_in[2];
    const float* conv_b     = (const float*)d_in[3];
    const float* x_proj_w   = (const float*)d_in[4];
    const float* dt_projs_w = (const float*)d_in[5];
    const float* dt_projs_b = (const float*)d_in[6];
    const float* A_logs     = (const float*)d_in[7];
    const float* Ds         = (const float*)d_in[8];
    const float* ln_g       = (const float*)d_in[9];
    const float* ln_b       = (const float*)d_in[10];
    const float* out_proj_w = (const float*)d_in[11];
    float* out = (float*)d_out;

    float* xct  = (float*)d_ws;            // 4,194,304 floats
    float* zb   = xct + 4194304;           // 4,194,304 floats
    float* xdbl = zb  + 4194304;           // 1,179,648 floats
    float* yg   = xdbl + 1179648;          // 16,777,216 floats
    const size_t need = (size_t)(4194304+4194304+1179648+16777216) * 4;

    k1_gemm<<<dim3(2048), dim3(512), 0, stream>>>(x, in_proj_w, conv_w, conv_b, xct, zb);
    k2_xproj<<<dim3(2048), dim3(256), 0, stream>>>(xct, x_proj_w, xdbl);

    if (ws_size >= need) {
        k3a_scan<<<dim3(512), dim3(512), 0, stream>>>(
            xct, xdbl, dt_projs_w, dt_projs_b, A_logs, yg);
        k3b_post<<<dim3(512), dim3(512), 0, stream>>>(
            yg, xct, zb, Ds, ln_g, ln_b, out_proj_w, out);
    } else {
        k3_fused<<<dim3(512), dim3(512), 0, stream>>>(
            xct, zb, xdbl, dt_projs_w, dt_projs_b, A_logs, Ds, ln_g, ln_b,
            out_proj_w, out);
    }
}

// Round 9
// 157.327 us; speedup vs baseline: 8.1992x; 1.0242x over previous
//
#include <hip/hip_runtime.h>

#define L_HW (128*128)

__device__ __forceinline__ int transp(int p){ return ((p&7)<<3)|(p>>3); }

// ================= K1: in_proj GEMM quarters (+conv+silu for xc) =================
#define K1_XIN  0
#define K1_WBUF 4352
#define K1_XCP  8448
#define K1_XOUT 0
#define K1_SMEM 12608

__global__ __launch_bounds__(512, 4)
void k1_gemm(const float* __restrict__ x,
             const float* __restrict__ in_proj_w,
             const float* __restrict__ conv_w,
             const float* __restrict__ conv_b,
             float* __restrict__ xct_g,   // [win][64p][128d]
             float* __restrict__ z_g)     // [win][128d][64p]
{
    __shared__ float sm[K1_SMEM];
    const int t = threadIdx.x;
    const int win = blockIdx.x >> 2, q = blockIdx.x & 3;
    const int b = win >> 8, ih = (win >> 4) & 15, iw = win & 15;
    const float* xwin = x + ((size_t)b*64)*L_HW + ih*8*128 + iw*8;

    {
        const int ch = t >> 3, r = t & 7;
        const float* src = xwin + (size_t)ch*L_HW + r*128;
        float4 v0 = *(const float4*)(src);
        float4 v1 = *(const float4*)(src + 4);
        float* dst = sm + K1_XIN + ch;
        const int p0 = r*8;
        dst[(p0+0)*68]=v0.x; dst[(p0+1)*68]=v0.y; dst[(p0+2)*68]=v0.z; dst[(p0+3)*68]=v0.w;
        dst[(p0+4)*68]=v1.x; dst[(p0+5)*68]=v1.y; dst[(p0+6)*68]=v1.z; dst[(p0+7)*68]=v1.w;
    }
    {
        const float* wsrc = in_proj_w + q*4096;
        *(float4*)(sm + K1_WBUF + t*4)        = *(const float4*)(wsrc + t*4);
        *(float4*)(sm + K1_WBUF + (t+512)*4)  = *(const float4*)(wsrc + (t+512)*4);
    }
    __syncthreads();

    const int p = t & 63, og = t >> 6;
    float a0=0,a1=0,a2=0,a3=0,a4=0,a5=0,a6=0,a7=0;
    {
        const float* wrow = sm + K1_WBUF + og*8*64;
#define K1ACC(J, A) { float4 wv = *(const float4*)(wrow + (J)*64 + chq*4); \
        A = fmaf(xv.x,wv.x, fmaf(xv.y,wv.y, fmaf(xv.z,wv.z, fmaf(xv.w,wv.w, A)))); }
        #pragma unroll
        for (int chq = 0; chq < 16; ++chq) {
            float4 xv = *(const float4*)(sm + K1_XIN + p*68 + chq*4);
            K1ACC(0,a0) K1ACC(1,a1) K1ACC(2,a2) K1ACC(3,a3)
            K1ACC(4,a4) K1ACC(5,a5) K1ACC(6,a6) K1ACC(7,a7)
        }
#undef K1ACC
    }

    if (q >= 2) {
        float* zw = z_g + (size_t)win*8192 + ((q-2)*64)*64 + p;
        zw[(og*8+0)*64]=a0; zw[(og*8+1)*64]=a1; zw[(og*8+2)*64]=a2; zw[(og*8+3)*64]=a3;
        zw[(og*8+4)*64]=a4; zw[(og*8+5)*64]=a5; zw[(og*8+6)*64]=a6; zw[(og*8+7)*64]=a7;
        return;
    }

    {
        float* xp = sm + K1_XCP + og*8*65 + p;
        xp[0]=a0; xp[65]=a1; xp[130]=a2; xp[195]=a3;
        xp[260]=a4; xp[325]=a5; xp[390]=a6; xp[455]=a7;
    }
    __syncthreads();

    {
        const int dloc = t & 63, qq = t >> 6;
        const int dg = q*64 + dloc;
        const float* cwp = conv_w + dg*9;
        const float c0=cwp[0],c1=cwp[1],c2=cwp[2],c3=cwp[3],c4=cwp[4],
                    c5=cwp[5],c6=cwp[6],c7=cwp[7],c8=cwp[8];
        const float cb = conv_b[dg];
        const float* xc = sm + K1_XCP + dloc*65;
        #pragma unroll
        for (int jj = 0; jj < 8; ++jj) {
            const int px = qq*8 + jj;
            const int r = px >> 3, c = px & 7;
            float a = cb;
            if (r > 0) {
                if (c > 0) a = fmaf(xc[px-9], c0, a);
                a = fmaf(xc[px-8], c1, a);
                if (c < 7) a = fmaf(xc[px-7], c2, a);
            }
            if (c > 0) a = fmaf(xc[px-1], c3, a);
            a = fmaf(xc[px], c4, a);
            if (c < 7) a = fmaf(xc[px+1], c5, a);
            if (r < 7) {
                if (c > 0) a = fmaf(xc[px+7], c6, a);
                a = fmaf(xc[px+8], c7, a);
                if (c < 7) a = fmaf(xc[px+9], c8, a);
            }
            sm[K1_XOUT + px*68 + dloc] = a / (1.f + __expf(-a));
        }
    }
    __syncthreads();

    {
        float* dst = xct_g + (size_t)win*8192 + q*64;
        #pragma unroll
        for (int i = 0; i < 2; ++i) {
            const int idx4 = i*512 + t;
            const int pp = idx4 >> 4, dg = idx4 & 15;
            float4 v = *(const float4*)(sm + K1_XOUT + pp*68 + dg*4);
            *(float4*)(dst + pp*128 + dg*4) = v;
        }
    }
}

// ================= K2: x_proj GEMM (operands in LDS) =================
#define K2_WL 4096
#define K2_XD 6400
#define K2_SMEM 8768

__global__ __launch_bounds__(256, 4)
void k2_xproj(const float* __restrict__ xct_g,
              const float* __restrict__ x_proj_w,
              float* __restrict__ xdbl_g)   // [win][4k][64l][36]
{
    __shared__ float sm[K2_SMEM];
    const int t = threadIdx.x;
    const int win = blockIdx.x >> 2, k = blockIdx.x & 3;
    const int p = t & 63, jg = t >> 6;
    float a0=0,a1=0,a2=0,a3=0,a4=0,a5=0,a6=0,a7=0,a8=0;

    for (int h = 0; h < 2; ++h) {
        __syncthreads();
        #pragma unroll
        for (int i = 0; i < 4; ++i) {
            const int idx4 = i*256 + t;
            const int pp = idx4 >> 4, dg = idx4 & 15;
            float4 v = *(const float4*)(xct_g + (size_t)win*8192 + pp*128 + h*64 + dg*4);
            *(float4*)(sm + pp*64 + ((dg ^ (pp&7))<<2)) = v;
        }
        #pragma unroll
        for (int i = 0; i < 3; ++i) {
            const int idx4 = i*256 + t;
            if (idx4 < 576) {
                const int r = idx4 >> 4, dg = idx4 & 15;
                float4 v = *(const float4*)(x_proj_w + (size_t)(k*36 + r)*128 + h*64 + dg*4);
                *(float4*)(sm + K2_WL + r*64 + dg*4) = v;
            }
        }
        __syncthreads();
        const float* wb = sm + K2_WL + jg*9*64;
#define K2ACC(J, A) { float4 wv = *(const float4*)(wb + (J)*64 + dg*4); \
        A = fmaf(xv.x,wv.x, fmaf(xv.y,wv.y, fmaf(xv.z,wv.z, fmaf(xv.w,wv.w, A)))); }
        #pragma unroll
        for (int dg = 0; dg < 16; ++dg) {
            float4 xv = *(const float4*)(sm + p*64 + ((dg ^ (p&7))<<2));
            K2ACC(0,a0) K2ACC(1,a1) K2ACC(2,a2) K2ACC(3,a3) K2ACC(4,a4)
            K2ACC(5,a5) K2ACC(6,a6) K2ACC(7,a7) K2ACC(8,a8)
        }
#undef K2ACC
    }
    __syncthreads();

    {
        const int l = (k==0) ? p : (k==1) ? transp(p) : (k==2) ? (63-p) : (63 - transp(p));
        float* dp = sm + K2_XD + l*37 + jg*9;
        dp[0]=a0; dp[1]=a1; dp[2]=a2; dp[3]=a3; dp[4]=a4;
        dp[5]=a5; dp[6]=a6; dp[7]=a7; dp[8]=a8;
    }
    __syncthreads();

    {
        float* dst = xdbl_g + ((size_t)win*4 + k)*2304;
        #pragma unroll
        for (int i = 0; i < 9; ++i) {
            const int idx = i*256 + t;
            const int l2 = idx / 36, c = idx - l2*36;
            dst[idx] = sm[K2_XD + l2*37 + c];
        }
    }
}

// ================= K3: fused scan + merge + LN + gate + out_proj =================
// LDS floats: XD [4k][64l][36] @0 (9216, overlaid by YM[128][65]=8320 after scan)
//             U  [64p][128d]   @9216 (8192)
//             MU @17408, RS @17472
#define F_XD 0
#define F_YM 0
#define F_U  9216
#define F_MU 17408
#define F_RS 17472
#define F_SMEM 17536

#define HSTEP(I, E, BC, CC) { h##I = fmaf(h##I, (E), dtu*(BC)); y = fmaf(h##I, (CC), y); }

__global__ __launch_bounds__(512, 4)
void k3_all(const float* __restrict__ xct_g,
            const float* __restrict__ z_g,
            const float* __restrict__ xdbl_g,
            const float* __restrict__ dt_projs_w,
            const float* __restrict__ dt_projs_b,
            const float* __restrict__ A_logs,
            const float* __restrict__ Ds,
            const float* __restrict__ ln_g,
            const float* __restrict__ ln_b,
            const float* __restrict__ out_proj_w,
            float* __restrict__ y_g,     // [win][4k][64l][128d] scratch
            float* __restrict__ out)
{
    __shared__ float sm[F_SMEM];
    const int t = threadIdx.x;
    const int win = blockIdx.x;

    // ---- phase 0: stage xdbl + u(xct) into LDS ----
    #pragma unroll
    for (int i = 0; i < 5; ++i) {
        const int idx4 = i*512 + t;
        if (idx4 < 2304) {
            float4 v = *(const float4*)(xdbl_g + (size_t)win*9216 + idx4*4);
            *(float4*)(sm + F_XD + idx4*4) = v;
        }
    }
    #pragma unroll
    for (int i = 0; i < 4; ++i) {
        const int idx4 = i*512 + t;
        float4 v = *(const float4*)(xct_g + (size_t)win*8192 + idx4*4);
        *(float4*)(sm + F_U + idx4*4) = v;
    }
    __syncthreads();

    // ---- phase 1: scan, y -> global (stays warm in this XCD's L2) ----
    {
        const int k = t >> 7, d = t & 127;
        const int kd = t;
        const float* alp = A_logs + kd*16;
        const float A0 = -__expf(alp[0]);
        bool fast = true;
        #pragma unroll
        for (int s = 1; s < 16; ++s) {
            float a = -__expf(alp[s]);
            fast = fast && (fabsf(a - (float)(s+1)*A0) <= 1e-4f * fabsf(a));
        }
        const float4 wv = *(const float4*)(dt_projs_w + kd*4);
        const float dtb = dt_projs_b[kd];
        float h0=0,h1=0,h2=0,h3=0,h4=0,h5=0,h6=0,h7=0,
              h8=0,h9=0,h10=0,h11=0,h12=0,h13=0,h14=0,h15=0;
        const float* XDk = sm + F_XD + k*2304;
        const float* ul = sm + F_U + d;
        float* yw = y_g + ((size_t)win*4 + k)*8192 + d;

        if (fast) {
            for (int l = 0; l < 64; ++l) {
                const float* row = XDk + l*36;
                float4 d4 = *(const float4*)(row);
                float4 b0 = *(const float4*)(row+4),  b1 = *(const float4*)(row+8);
                float4 b2 = *(const float4*)(row+12), b3 = *(const float4*)(row+16);
                float4 c0 = *(const float4*)(row+20), c1 = *(const float4*)(row+24);
                float4 c2 = *(const float4*)(row+28), c3 = *(const float4*)(row+32);
                float dtraw = dtb + wv.x*d4.x + wv.y*d4.y + wv.z*d4.z + wv.w*d4.w;
                float dt = (dtraw > 20.f) ? dtraw : __logf(1.f + __expf(dtraw));
                const int lr = 63 - l;
                const int p = (k==0)?l : (k==1)?transp(l) : (k==2)?lr : transp(lr);
                const float u = ul[p*128];
                const float dtu = dt * u;
                const float r  = __expf(dt * A0);
                const float r2 = r*r, r4 = r2*r2, r8 = r4*r4;
                const float e3 = r2*r, e5 = r4*r, e6 = r4*r2, e7 = r4*e3;
                const float e9 = r8*r, e10 = r8*r2, e11 = r8*e3, e12 = r8*r4;
                const float e13 = r8*e5, e14 = r8*e6, e15 = r8*e7, e16 = r8*r8;
                float y = 0.f;
                HSTEP(0,  r,   b0.x, c0.x)  HSTEP(1,  r2,  b0.y, c0.y)
                HSTEP(2,  e3,  b0.z, c0.z)  HSTEP(3,  r4,  b0.w, c0.w)
                HSTEP(4,  e5,  b1.x, c1.x)  HSTEP(5,  e6,  b1.y, c1.y)
                HSTEP(6,  e7,  b1.z, c1.z)  HSTEP(7,  r8,  b1.w, c1.w)
                HSTEP(8,  e9,  b2.x, c2.x)  HSTEP(9,  e10, b2.y, c2.y)
                HSTEP(10, e11, b2.z, c2.z)  HSTEP(11, e12, b2.w, c2.w)
                HSTEP(12, e13, b3.x, c3.x)  HSTEP(13, e14, b3.y, c3.y)
                HSTEP(14, e15, b3.z, c3.z)  HSTEP(15, e16, b3.w, c3.w)
                yw[l*128] = y;
            }
        } else {
            const float A1=-__expf(alp[1]), A2=-__expf(alp[2]), A3=-__expf(alp[3]),
                        A4=-__expf(alp[4]), A5=-__expf(alp[5]), A6=-__expf(alp[6]),
                        A7=-__expf(alp[7]), A8=-__expf(alp[8]), A9=-__expf(alp[9]),
                        A10=-__expf(alp[10]), A11=-__expf(alp[11]), A12=-__expf(alp[12]),
                        A13=-__expf(alp[13]), A14=-__expf(alp[14]), A15=-__expf(alp[15]);
            for (int l = 0; l < 64; ++l) {
                const float* row = XDk + l*36;
                float4 d4 = *(const float4*)(row);
                float4 b0 = *(const float4*)(row+4),  b1 = *(const float4*)(row+8);
                float4 b2 = *(const float4*)(row+12), b3 = *(const float4*)(row+16);
                float4 c0 = *(const float4*)(row+20), c1 = *(const float4*)(row+24);
                float4 c2 = *(const float4*)(row+28), c3 = *(const float4*)(row+32);
                float dtraw = dtb + wv.x*d4.x + wv.y*d4.y + wv.z*d4.z + wv.w*d4.w;
                float dt = (dtraw > 20.f) ? dtraw : __logf(1.f + __expf(dtraw));
                const int lr = 63 - l;
                const int p = (k==0)?l : (k==1)?transp(l) : (k==2)?lr : transp(lr);
                const float u = ul[p*128];
                const float dtu = dt * u;
                float y = 0.f;
                HSTEP(0,  __expf(dt*A0),  b0.x, c0.x)  HSTEP(1,  __expf(dt*A1),  b0.y, c0.y)
                HSTEP(2,  __expf(dt*A2),  b0.z, c0.z)  HSTEP(3,  __expf(dt*A3),  b0.w, c0.w)
                HSTEP(4,  __expf(dt*A4),  b1.x, c1.x)  HSTEP(5,  __expf(dt*A5),  b1.y, c1.y)
                HSTEP(6,  __expf(dt*A6),  b1.z, c1.z)  HSTEP(7,  __expf(dt*A7),  b1.w, c1.w)
                HSTEP(8,  __expf(dt*A8),  b2.x, c2.x)  HSTEP(9,  __expf(dt*A9),  b2.y, c2.y)
                HSTEP(10, __expf(dt*A10), b2.z, c2.z)  HSTEP(11, __expf(dt*A11), b2.w, c2.w)
                HSTEP(12, __expf(dt*A12), b3.x, c3.x)  HSTEP(13, __expf(dt*A13), b3.y, c3.y)
                HSTEP(14, __expf(dt*A14), b3.z, c3.z)  HSTEP(15, __expf(dt*A15), b3.w, c3.w)
                yw[l*128] = y;
            }
        }
    }
    __syncthreads();   // orders global y writes block-wide; xdbl now dead

    // ---- phase 2: gather-merge into YM (overlays XD region) ----
    {
        const int d2 = t & 127, pq = t >> 7;
        const float Dsum = Ds[d2] + Ds[128+d2] + Ds[256+d2] + Ds[384+d2];
        const float* yg0 = y_g + ((size_t)win*4 + 0)*8192 + d2;
        const float* yg1 = y_g + ((size_t)win*4 + 1)*8192 + d2;
        const float* yg2 = y_g + ((size_t)win*4 + 2)*8192 + d2;
        const float* yg3 = y_g + ((size_t)win*4 + 3)*8192 + d2;
        const float* uc  = sm + F_U + d2;
        #pragma unroll
        for (int i = 0; i < 16; ++i) {
            const int p = pq*16 + i;
            const int tp = transp(p);
            float v = yg0[p*128] + yg1[tp*128] + yg2[(63-p)*128] + yg3[(63-tp)*128]
                    + Dsum * uc[p*128];
            sm[F_YM + d2*65 + p] = v;
        }
    }
    __syncthreads();

    // ---- phase 3a: LN stats ----
    {
        const int px = t >> 3, j = t & 7;
        float s1 = 0.f, s2 = 0.f;
        #pragma unroll
        for (int i = 0; i < 16; ++i) {
            float v = sm[F_YM + (j*16 + i)*65 + px];
            s1 += v; s2 += v*v;
        }
        s1 += __shfl_xor(s1,1); s2 += __shfl_xor(s2,1);
        s1 += __shfl_xor(s1,2); s2 += __shfl_xor(s2,2);
        s1 += __shfl_xor(s1,4); s2 += __shfl_xor(s2,4);
        if (j == 0) {
            float mu  = s1 * 0.0078125f;
            float var = s2 * 0.0078125f - mu*mu;
            sm[F_MU + px] = mu;
            sm[F_RS + px] = rsqrtf(var + 1e-5f);
        }
    }
    __syncthreads();

    // ---- phase 3b: yhat = LN(y) * silu(z) ----
    {
        const int p = t & 63, dblk = (t >> 6) * 16;
        const float mu = sm[F_MU + p], rs = sm[F_RS + p];
        const float* zb = z_g + (size_t)win*8192 + p;
        #pragma unroll
        for (int i = 0; i < 16; ++i) {
            const int d = dblk + i;
            float yv = sm[F_YM + d*65 + p];
            float yh = (yv - mu)*rs*ln_g[d] + ln_b[d];
            float zv = zb[d*64];
            sm[F_YM + d*65 + p] = yh * (zv / (1.f + __expf(-zv)));
        }
    }
    __syncthreads();

    // ---- phase 3c: out_proj ----
    {
        const int p = t & 63, m0 = (t >> 6) * 8;
        float o0=0,o1=0,o2=0,o3=0,o4=0,o5=0,o6=0,o7=0;
#define OACC(J, O) { float4 wq = *(const float4*)(out_proj_w + (m0+(J))*128 + dq*4); \
        O = fmaf(y0,wq.x, fmaf(y1,wq.y, fmaf(y2,wq.z, fmaf(y3,wq.w, O)))); }
        #pragma unroll
        for (int dq = 0; dq < 32; ++dq) {
            float y0 = sm[F_YM + (dq*4+0)*65 + p];
            float y1 = sm[F_YM + (dq*4+1)*65 + p];
            float y2 = sm[F_YM + (dq*4+2)*65 + p];
            float y3 = sm[F_YM + (dq*4+3)*65 + p];
            OACC(0,o0) OACC(1,o1) OACC(2,o2) OACC(3,o3)
            OACC(4,o4) OACC(5,o5) OACC(6,o6) OACC(7,o7)
        }
#undef OACC
        const int b = win >> 8, ih = (win>>4)&15, iw = win&15;
        float* op = out + ((size_t)b*64)*L_HW + (ih*8 + (p>>3))*128 + iw*8 + (p&7);
        op[(size_t)(m0+0)*L_HW]=o0; op[(size_t)(m0+1)*L_HW]=o1;
        op[(size_t)(m0+2)*L_HW]=o2; op[(size_t)(m0+3)*L_HW]=o3;
        op[(size_t)(m0+4)*L_HW]=o4; op[(size_t)(m0+5)*L_HW]=o5;
        op[(size_t)(m0+6)*L_HW]=o6; op[(size_t)(m0+7)*L_HW]=o7;
    }
}
#undef HSTEP

extern "C" void kernel_launch(void* const* d_in, const int* in_sizes, int n_in,
                              void* d_out, int out_size, void* d_ws, size_t ws_size,
                              hipStream_t stream) {
    const float* x          = (const float*)d_in[0];
    const float* in_proj_w  = (const float*)d_in[1];
    const float* conv_w     = (const float*)d_in[2];
    const float* conv_b     = (const float*)d_in[3];
    const float* x_proj_w   = (const float*)d_in[4];
    const float* dt_projs_w = (const float*)d_in[5];
    const float* dt_projs_b = (const float*)d_in[6];
    const float* A_logs     = (const float*)d_in[7];
    const float* Ds         = (const float*)d_in[8];
    const float* ln_g       = (const float*)d_in[9];
    const float* ln_b       = (const float*)d_in[10];
    const float* out_proj_w = (const float*)d_in[11];
    float* out = (float*)d_out;

    float* xct  = (float*)d_ws;            // 4,194,304 floats
    float* zb   = xct + 4194304;           // 4,194,304 floats
    float* xdbl = zb  + 4194304;           // 1,179,648 floats
    float* yg   = xdbl + 1179648;          // 16,777,216 floats

    k1_gemm<<<dim3(2048), dim3(512), 0, stream>>>(x, in_proj_w, conv_w, conv_b, xct, zb);
    k2_xproj<<<dim3(2048), dim3(256), 0, stream>>>(xct, x_proj_w, xdbl);
    k3_all<<<dim3(512), dim3(512), 0, stream>>>(
        xct, zb, xdbl, dt_projs_w, dt_projs_b, A_logs, Ds, ln_g, ln_b,
        out_proj_w, yg, out);
}